// Round 9
// baseline (102.494 us; speedup 1.0000x reference)
//
#include <hip/hip_runtime.h>
#include <hip/hip_bf16.h>
#include <hip/hip_fp16.h>

#define B_    512
#define NI    1152
#define NO    10
#define BT    16
#define NBT   32           // B_/BT
#define NC    24           // chunks (8 XCD x 3)
#define NCH   48           // n per chunk
#define RNDS  12
#define RN    4            // n per staged round (1 per wave)

#define WBUF_US 6144       // W round image: 12 granules * 512 us
#define XBUF_US 512        // x round image: 4 n * 128 us
#define BUF_US  6656       // W + x (13,312 B per buffer)

typedef __attribute__((ext_vector_type(8))) short bf16x8;
typedef __attribute__((ext_vector_type(4))) float f32x4;
typedef __attribute__((ext_vector_type(8))) unsigned short u16x8;

// workspace element counts
#define SPART_H    ((size_t)NC * NBT * NO * 256)      // 1,966,080 halfs (3.93 MB)
#define OUTSUM_F32 ((size_t)NBT * NO * 256)           //    81,920 f32  (0.33 MB)
#define XB_US      ((size_t)NBT * NC * RNDS * XBUF_US)// 4,718,592 us   (9.44 MB)
#define WB_US      ((size_t)NC * RNDS * WBUF_US)      // 1,769,472 us   (3.54 MB)

__device__ inline unsigned short f2bf(float f) {
    __hip_bfloat16 h = __float2bfloat16(f);
    return *reinterpret_cast<unsigned short*>(&h);
}

__device__ inline void gld_lds16(const void* g, void* lds) {
    __builtin_amdgcn_global_load_lds(
        (const __attribute__((address_space(1))) void*)g,
        (__attribute__((address_space(3))) void*)lds, 16, 0, 0);
}

// Fused conversion. Blocks [0,2304): x -> xb; [2304,3168): w -> wb.
// xb image per (bt,nc,r): 512 us, [nl*128 + bl*8], nl in 0..3.
// wb image per (nc,r): 6144 us, [(nl*3+oq)*512 + (hi*16+d)*8], o = 4*oq+hi.
__global__ __launch_bounds__(256) void cvt_xw(
    const float* __restrict__ x, const float* __restrict__ w,
    unsigned short* __restrict__ xb, unsigned short* __restrict__ wb)
{
    const int blk = blockIdx.x;
    if (blk < 2304) {
        const int t   = blk * 256 + threadIdx.x;   // 589,824 granules
        const int m   = t & 63;
        const int img = t >> 6;                    // (bt*NC+nc)*12+r
        const int nl  = m >> 4, bl = m & 15;
        const int r   = img % RNDS;
        const int bc  = img / RNDS;
        const int nc  = bc % NC, bt = bc / NC;
        const int b   = bt * BT + bl;
        const int n   = nc * NCH + r * RN + nl;
        const float* src = x + ((size_t)b * NI + n) * 8;
        float4 v0 = *reinterpret_cast<const float4*>(src);
        float4 v1 = *reinterpret_cast<const float4*>(src + 4);
        u16x8 u = { f2bf(v0.x), f2bf(v0.y), f2bf(v0.z), f2bf(v0.w),
                    f2bf(v1.x), f2bf(v1.y), f2bf(v1.z), f2bf(v1.w) };
        *reinterpret_cast<u16x8*>(xb + (size_t)t * 8) = u;
    } else {
        const int t    = (blk - 2304) * 256 + threadIdx.x;  // 221,184 granules
        const int lane = t & 63;
        const int gs   = (t >> 6) % 12;
        const int img  = t / 768;                  // nc*12+r
        const int hi   = lane >> 4, d = lane & 15;
        const int nl   = gs / 3, oq = gs % 3;
        const int r    = img % RNDS, nc = img / RNDS;
        const int o    = oq * 4 + hi;
        const int n    = nc * NCH + r * RN + nl;
        u16x8 u = {0,0,0,0,0,0,0,0};
        if (o < NO) {
            const float* src = w + ((size_t)o * NI + n) * 128 + d * 8;
            float4 v0 = *reinterpret_cast<const float4*>(src);
            float4 v1 = *reinterpret_cast<const float4*>(src + 4);
            u = (u16x8){ f2bf(v0.x), f2bf(v0.y), f2bf(v0.z), f2bf(v0.w),
                         f2bf(v1.x), f2bf(v1.y), f2bf(v1.z), f2bf(v1.w) };
        }
        *reinterpret_cast<u16x8*>(wb + (size_t)t * 8) = u;
    }
}

union LdsU {
    unsigned short stage[2 * BUF_US];   // 26,624 B (double-buffered rounds)
    uint2 red[4][NO * 64];              // 20,480 B (fp16-packed epilogue)
};

// One routing iteration. Block = bt x nc; 12 double-buffered rounds of 4 n
// (1 n per wave). Round r+1's global_load_lds issued before round r's
// compute; single vmcnt(0)+barrier per round.
template<bool UNIFORM>
__global__ __launch_bounds__(256, 4) void caps_iter(
    const unsigned short* __restrict__ xb,
    const unsigned short* __restrict__ wb,
    const float* __restrict__ outsum,    // [bt*10+o][64][4] lane-major f32
    unsigned short* __restrict__ s_part) // [nc][bt][o][64][4] fp16
{
    __shared__ LdsU lds;

    const int tid = threadIdx.x;
    const int w   = tid >> 6;
    const int l   = tid & 63;
    const int b16 = l & 15;
    const int hi  = l >> 4;
    const int blk = blockIdx.x;
    const int xcd = blk & 7, idx = blk >> 3;     // XCD owns 3 chunks
    const int nc  = xcd * 3 + (idx >> 5);
    const int bt  = idx & 31;

    const unsigned short* wsrc = wb + (size_t)nc * (RNDS * WBUF_US);
    const unsigned short* xsrc = xb + ((size_t)bt * NC + nc) * (RNDS * XBUF_US);

    auto stage = [&](int r, int kbuf) {
        const unsigned short* wr = wsrc + (size_t)r * WBUF_US;
        char* dst = (char*)lds.stage + kbuf * (BUF_US * 2);
        #pragma unroll
        for (int k = 0; k < 3; ++k)          // 768 16B chunks of W
            gld_lds16(wr + (k * 256 + tid) * 8, dst + (k * 256 + tid) * 16);
        if (tid < 64)                        // 64 16B chunks of x
            gld_lds16(xsrc + (size_t)r * XBUF_US + tid * 8,
                      dst + WBUF_US * 2 + tid * 16);
    };

    f32x4 outf[NO];
    if constexpr (!UNIFORM) {
        #pragma unroll
        for (int o = 0; o < NO; ++o)
            outf[o] = *reinterpret_cast<const f32x4*>(
                outsum + (((size_t)bt * NO + o) * 64 + l) * 4);
    }

    f32x4 sacc[NO];
    #pragma unroll
    for (int o = 0; o < NO; ++o) sacc[o] = (f32x4){0.f, 0.f, 0.f, 0.f};

    stage(0, 0);
    asm volatile("s_waitcnt vmcnt(0)" ::: "memory");
    __syncthreads();

    #pragma unroll 1
    for (int r = 0; r < RNDS; ++r) {
        if (r + 1 < RNDS) stage(r + 1, (r + 1) & 1);   // prefetch next round

        const int ub = (r & 1) * BUF_US;               // this round's buffer

        // this wave's n: nl = w. x broadcast (16 lanes same addr), mask per k.
        bf16x8 bv = *reinterpret_cast<const bf16x8*>(
            &lds.stage[ub + WBUF_US + w * 128 + b16 * 8]);
        bf16x8 bvt[4];
        #pragma unroll
        for (int t = 0; t < 4; ++t)
            bvt[t] = (hi == t) ? bv : (bf16x8){0,0,0,0,0,0,0,0};

        if constexpr (UNIFORM) {
            #pragma unroll
            for (int oq = 0; oq < 3; ++oq) {
                bf16x8 av = *reinterpret_cast<const bf16x8*>(
                    &lds.stage[ub + (w * 3 + oq) * 512 + l * 8]);
                const int tmax = (oq < 2) ? 4 : 2;
                #pragma unroll
                for (int t = 0; t < tmax; ++t)
                    sacc[oq * 4 + t] = __builtin_amdgcn_mfma_f32_16x16x32_bf16(
                        av, bvt[t], sacc[oq * 4 + t], 0, 0, 0);
            }
        } else {
            float lg[NO];
            #pragma unroll
            for (int oq = 0; oq < 3; ++oq) {
                bf16x8 av = *reinterpret_cast<const bf16x8*>(
                    &lds.stage[ub + (w * 3 + oq) * 512 + l * 8]);
                const int tmax = (oq < 2) ? 4 : 2;
                #pragma unroll
                for (int t = 0; t < tmax; ++t) {
                    f32x4 xh = __builtin_amdgcn_mfma_f32_16x16x32_bf16(
                        av, bvt[t], (f32x4){0.f, 0.f, 0.f, 0.f}, 0, 0, 0);
                    const int o = oq * 4 + t;
                    float pp = outf[o][0] * xh[0];
                    pp = fmaf(outf[o][1], xh[1], pp);
                    pp = fmaf(outf[o][2], xh[2], pp);
                    pp = fmaf(outf[o][3], xh[3], pp);
                    pp += __shfl_xor(pp, 16, 64);
                    pp += __shfl_xor(pp, 32, 64);
                    lg[o] = pp;
                }
            }
            float sum = 0.f;
            #pragma unroll
            for (int o = 0; o < NO; ++o) { lg[o] = __expf(lg[o]); sum += lg[o]; }
            const float rs = __builtin_amdgcn_rcpf(sum);
            #pragma unroll
            for (int oq = 0; oq < 3; ++oq) {
                bf16x8 av = *reinterpret_cast<const bf16x8*>(
                    &lds.stage[ub + (w * 3 + oq) * 512 + l * 8]);
                const int tmax = (oq < 2) ? 4 : 2;
                #pragma unroll
                for (int t = 0; t < tmax; ++t) {
                    f32x4 xh = __builtin_amdgcn_mfma_f32_16x16x32_bf16(
                        av, bvt[t], (f32x4){0.f, 0.f, 0.f, 0.f}, 0, 0, 0);
                    const int o = oq * 4 + t;
                    const float cc = lg[o] * rs;
                    sacc[o][0] = fmaf(cc, xh[0], sacc[o][0]);
                    sacc[o][1] = fmaf(cc, xh[1], sacc[o][1]);
                    sacc[o][2] = fmaf(cc, xh[2], sacc[o][2]);
                    sacc[o][3] = fmaf(cc, xh[3], sacc[o][3]);
                }
            }
        }

        // prefetched loads have had a full round of compute to land
        asm volatile("s_waitcnt vmcnt(0)" ::: "memory");
        __syncthreads();
    }

    // cross-wave reduce, fp16-packed (uint2/o), lane-consecutive = conflict-free
    const float sc = UNIFORM ? 0.1f : 1.0f;
    #pragma unroll
    for (int o = 0; o < NO; ++o) {
        __half2 h01 = __floats2half2_rn(sacc[o][0] * sc, sacc[o][1] * sc);
        __half2 h23 = __floats2half2_rn(sacc[o][2] * sc, sacc[o][3] * sc);
        lds.red[w][o * 64 + l] =
            make_uint2(*reinterpret_cast<unsigned int*>(&h01),
                       *reinterpret_cast<unsigned int*>(&h23));
    }
    __syncthreads();
    unsigned short* base = s_part + ((size_t)nc * NBT + bt) * 2560;
    for (int g = tid; g < NO * 64; g += 256) {
        uint2 a0 = lds.red[0][g], a1 = lds.red[1][g],
              a2 = lds.red[2][g], a3 = lds.red[3][g];
        auto h2f2 = [](unsigned int u) {
            __half2 h = *reinterpret_cast<__half2*>(&u);
            return __half22float2(h);
        };
        float2 lo = h2f2(a0.x), l1 = h2f2(a1.x), l2 = h2f2(a2.x), l3 = h2f2(a3.x);
        float2 ho = h2f2(a0.y), h1 = h2f2(a1.y), h2 = h2f2(a2.y), h3 = h2f2(a3.y);
        float2 sl = { (lo.x + l1.x) + (l2.x + l3.x), (lo.y + l1.y) + (l2.y + l3.y) };
        float2 sh = { (ho.x + h1.x) + (h2.x + h3.x), (ho.y + h1.y) + (h2.y + h3.y) };
        __half2 p01 = __floats2half2_rn(sl.x, sl.y);
        __half2 p23 = __floats2half2_rn(sh.x, sh.y);
        *reinterpret_cast<uint2*>(base + (size_t)g * 4) =
            make_uint2(*reinterpret_cast<unsigned int*>(&p01),
                       *reinterpret_cast<unsigned int*>(&p23));
    }
}

// Reduce chunks + squash. Block bo = bt*10+o; thread t: l=t>>2, q=t&3.
template<int MODE>
__global__ __launch_bounds__(256) void caps_squash(
    const unsigned short* __restrict__ s_part,
    float* __restrict__ outsum,
    float* __restrict__ dout)
{
    __shared__ float sq[256];
    const int bo = blockIdx.x;
    const int t  = threadIdx.x;

    float s = 0.f;
    #pragma unroll 4
    for (int nc = 0; nc < NC; ++nc) {
        __half h = *reinterpret_cast<const __half*>(
            s_part + ((size_t)nc * NBT * NO + bo) * 256 + t);
        s += __half2float(h);
    }

    float n2 = s * s;
    n2 += __shfl_xor(n2, 1, 64);
    n2 += __shfl_xor(n2, 2, 64);       // q-pair reduced
    sq[t] = n2;
    __syncthreads();
    const int base = t & 63;
    n2 = (sq[base] + sq[64 + base]) + (sq[128 + base] + sq[192 + base]);

    const float norm  = sqrtf(n2);
    const float scale = n2 / ((1.f + n2) * (norm + 1e-8f));
    const float v = scale * s;

    if constexpr (MODE == 0) {
        outsum[(size_t)bo * 256 + t] = v;
    } else if constexpr (MODE == 1) {
        outsum[(size_t)bo * 256 + t] += v;
    } else {
        const int bt = bo / NO, o = bo - bt * NO;
        const int b16 = (t >> 2) & 15, hi = t >> 6, q = t & 3;
        dout[((size_t)(bt * BT + b16) * NO + o) * 16 + hi * 4 + q] = v;
    }
}

extern "C" void kernel_launch(void* const* d_in, const int* in_sizes, int n_in,
                              void* d_out, int out_size, void* d_ws, size_t ws_size,
                              hipStream_t stream) {
    const float* x = (const float*)d_in[0];   // [512][1152][8]
    const float* w = (const float*)d_in[1];   // [10][1152][16][8]
    float* out = (float*)d_out;               // [512][10][16]

    unsigned short* s_part = (unsigned short*)d_ws;
    float*          outsum = (float*)(s_part + SPART_H);
    unsigned short* xb     = (unsigned short*)(outsum + OUTSUM_F32);
    unsigned short* wb     = xb + XB_US;      // total ws ~= 17.2 MB

    cvt_xw<<<dim3(3168), dim3(256), 0, stream>>>(x, w, xb, wb);

    dim3 gI(NBT * NC), bI(256);               // 768 blocks
    dim3 gS(NBT * NO), bS(256);               // 320 blocks

    caps_iter<true ><<<gI, bI, 0, stream>>>(xb, wb, nullptr, s_part);
    caps_squash<0><<<gS, bS, 0, stream>>>(s_part, outsum, nullptr);
    caps_iter<false><<<gI, bI, 0, stream>>>(xb, wb, outsum, s_part);
    caps_squash<1><<<gS, bS, 0, stream>>>(s_part, outsum, nullptr);
    caps_iter<false><<<gI, bI, 0, stream>>>(xb, wb, outsum, s_part);
    caps_squash<2><<<gS, bS, 0, stream>>>(s_part, nullptr, out);
}

// Round 10
// 77.588 us; speedup vs baseline: 1.3210x; 1.3210x over previous
//
#include <hip/hip_runtime.h>
#include <hip/hip_bf16.h>
#include <hip/hip_fp16.h>

#define B_    512
#define NI    1152
#define NO    10
#define BT    16
#define NBT   32           // B_/BT
#define NC    24           // chunks (8 XCD x 3)
#define NCH   48           // n per chunk
#define RNDS  6
#define RN    8            // n per staged round

#define WBUF_US 12288      // W round image: 24 granules * 512 us
#define XBUF_US 1024       // x round image: 8 n * 128 us
#define BUF_US  13312      // W + x (26,624 B per buffer)

typedef __attribute__((ext_vector_type(8))) short bf16x8;
typedef __attribute__((ext_vector_type(4))) float f32x4;
typedef __attribute__((ext_vector_type(8))) unsigned short u16x8;

// workspace element counts
#define SPART_H    ((size_t)NC * NBT * NO * 256)      // 1,966,080 halfs (3.93 MB)
#define OUTSUM_F32 ((size_t)NBT * NO * 256)           //    81,920 f32  (0.33 MB)
#define XB_US      ((size_t)NBT * NC * RNDS * XBUF_US)// 4,718,592 us   (9.44 MB)
#define WB_US      ((size_t)NC * RNDS * WBUF_US)      // 1,769,472 us   (3.54 MB)

__device__ inline unsigned short f2bf(float f) {
    __hip_bfloat16 h = __float2bfloat16(f);
    return *reinterpret_cast<unsigned short*>(&h);
}

__device__ inline void gld_lds16(const void* g, void* lds) {
    __builtin_amdgcn_global_load_lds(
        (const __attribute__((address_space(1))) void*)g,
        (__attribute__((address_space(3))) void*)lds, 16, 0, 0);
}

// Fused conversion. Blocks [0,2304): x -> xb round images; [2304,3168): w -> wb.
// xb image per (bt,nc,r): 1024 us, [nl*128 + bl*8].
// wb image per (nc,r): 12288 us, [(nl*3+oq)*512 + (hi*16+d)*8], o = 4*oq+hi.
__global__ __launch_bounds__(256) void cvt_xw(
    const float* __restrict__ x, const float* __restrict__ w,
    unsigned short* __restrict__ xb, unsigned short* __restrict__ wb)
{
    const int blk = blockIdx.x;
    if (blk < 2304) {
        const int t   = blk * 256 + threadIdx.x;   // 589,824 granules
        const int m   = t & 127;
        const int img = t >> 7;                    // (bt*NC+nc)*6+r
        const int nl  = m >> 4, bl = m & 15;
        const int r   = img % RNDS;
        const int bc  = img / RNDS;
        const int nc  = bc % NC, bt = bc / NC;
        const int b   = bt * BT + bl;
        const int n   = nc * NCH + r * RN + nl;
        const float* src = x + ((size_t)b * NI + n) * 8;
        float4 v0 = *reinterpret_cast<const float4*>(src);
        float4 v1 = *reinterpret_cast<const float4*>(src + 4);
        u16x8 u = { f2bf(v0.x), f2bf(v0.y), f2bf(v0.z), f2bf(v0.w),
                    f2bf(v1.x), f2bf(v1.y), f2bf(v1.z), f2bf(v1.w) };
        *reinterpret_cast<u16x8*>(xb + (size_t)t * 8) = u;
    } else {
        const int t    = (blk - 2304) * 256 + threadIdx.x;  // 221,184 granules
        const int lane = t & 63;
        const int gs   = (t >> 6) % 24;
        const int img  = t / 1536;                 // nc*6+r
        const int hi   = lane >> 4, d = lane & 15;
        const int nl   = gs / 3, oq = gs % 3;
        const int r    = img % RNDS, nc = img / RNDS;
        const int o    = oq * 4 + hi;
        const int n    = nc * NCH + r * RN + nl;
        u16x8 u = {0,0,0,0,0,0,0,0};
        if (o < NO) {
            const float* src = w + ((size_t)o * NI + n) * 128 + d * 8;
            float4 v0 = *reinterpret_cast<const float4*>(src);
            float4 v1 = *reinterpret_cast<const float4*>(src + 4);
            u = (u16x8){ f2bf(v0.x), f2bf(v0.y), f2bf(v0.z), f2bf(v0.w),
                         f2bf(v1.x), f2bf(v1.y), f2bf(v1.z), f2bf(v1.w) };
        }
        *reinterpret_cast<u16x8*>(wb + (size_t)t * 8) = u;
    }
}

union LdsU {
    unsigned short stage[2 * BUF_US];   // 53,248 B (double-buffered rounds)
    uint2 red[4][NO * 64];              // 20,480 B (fp16-packed epilogue)
};

// One routing iteration. Block = bt x nc; 6 double-buffered rounds of 8 n
// (2 n per wave). Round r+1's global_load_lds issued before round r's
// compute. Non-uniform path: single MFMA pass, xh kept in registers.
template<bool UNIFORM>
__global__ __launch_bounds__(256, 3) void caps_iter(
    const unsigned short* __restrict__ xb,
    const unsigned short* __restrict__ wb,
    const float* __restrict__ outsum,    // [bt*10+o][64][4] lane-major f32
    unsigned short* __restrict__ s_part) // [nc][bt][o][64][4] fp16
{
    __shared__ LdsU lds;

    const int tid = threadIdx.x;
    const int w   = tid >> 6;
    const int l   = tid & 63;
    const int b16 = l & 15;
    const int hi  = l >> 4;
    const int blk = blockIdx.x;
    const int xcd = blk & 7, idx = blk >> 3;     // XCD owns 3 chunks
    const int nc  = xcd * 3 + (idx >> 5);
    const int bt  = idx & 31;

    const unsigned short* wsrc = wb + (size_t)nc * (RNDS * WBUF_US);
    const unsigned short* xsrc = xb + ((size_t)bt * NC + nc) * (RNDS * XBUF_US);

    auto stage = [&](int r, int kbuf) {
        const unsigned short* wr = wsrc + (size_t)r * WBUF_US;
        char* dst = (char*)lds.stage + kbuf * (BUF_US * 2);
        #pragma unroll
        for (int k = 0; k < 6; ++k)          // 1536 16B chunks of W
            gld_lds16(wr + (k * 256 + tid) * 8, dst + (k * 256 + tid) * 16);
        if (tid < 128)                       // 128 16B chunks of x
            gld_lds16(xsrc + (size_t)r * XBUF_US + tid * 8,
                      dst + WBUF_US * 2 + tid * 16);
    };

    f32x4 outf[NO];
    if constexpr (!UNIFORM) {
        #pragma unroll
        for (int o = 0; o < NO; ++o)
            outf[o] = *reinterpret_cast<const f32x4*>(
                outsum + (((size_t)bt * NO + o) * 64 + l) * 4);
    }

    f32x4 sacc[NO];
    #pragma unroll
    for (int o = 0; o < NO; ++o) sacc[o] = (f32x4){0.f, 0.f, 0.f, 0.f};

    stage(0, 0);
    asm volatile("s_waitcnt vmcnt(0)" ::: "memory");
    __syncthreads();

    #pragma unroll 1
    for (int r = 0; r < RNDS; ++r) {
        if (r + 1 < RNDS) stage(r + 1, (r + 1) & 1);   // prefetch next round

        const int ub = (r & 1) * BUF_US;               // this round's buffer

        #pragma unroll 1
        for (int i = 0; i < 2; ++i) {
            const int nl = w * 2 + i;                  // wave's n within round
            bf16x8 bv = *reinterpret_cast<const bf16x8*>(
                &lds.stage[ub + WBUF_US + nl * 128 + b16 * 8]);
            bf16x8 bvt[4];
            #pragma unroll
            for (int t = 0; t < 4; ++t)
                bvt[t] = (hi == t) ? bv : (bf16x8){0,0,0,0,0,0,0,0};

            if constexpr (UNIFORM) {
                #pragma unroll
                for (int oq = 0; oq < 3; ++oq) {
                    bf16x8 av = *reinterpret_cast<const bf16x8*>(
                        &lds.stage[ub + (nl * 3 + oq) * 512 + l * 8]);
                    const int tmax = (oq < 2) ? 4 : 2;
                    #pragma unroll
                    for (int t = 0; t < tmax; ++t)
                        sacc[oq * 4 + t] = __builtin_amdgcn_mfma_f32_16x16x32_bf16(
                            av, bvt[t], sacc[oq * 4 + t], 0, 0, 0);
                }
            } else {
                f32x4 xh[NO];
                float lg[NO];
                // single MFMA pass: xh kept in registers, logits alongside
                #pragma unroll
                for (int oq = 0; oq < 3; ++oq) {
                    bf16x8 av = *reinterpret_cast<const bf16x8*>(
                        &lds.stage[ub + (nl * 3 + oq) * 512 + l * 8]);
                    const int tmax = (oq < 2) ? 4 : 2;
                    #pragma unroll
                    for (int t = 0; t < tmax; ++t) {
                        const int o = oq * 4 + t;
                        xh[o] = __builtin_amdgcn_mfma_f32_16x16x32_bf16(
                            av, bvt[t], (f32x4){0.f, 0.f, 0.f, 0.f}, 0, 0, 0);
                        float pp = outf[o][0] * xh[o][0];
                        pp = fmaf(outf[o][1], xh[o][1], pp);
                        pp = fmaf(outf[o][2], xh[o][2], pp);
                        pp = fmaf(outf[o][3], xh[o][3], pp);
                        pp += __shfl_xor(pp, 16, 64);
                        pp += __shfl_xor(pp, 32, 64);
                        lg[o] = pp;
                    }
                }
                float sum = 0.f;
                #pragma unroll
                for (int o = 0; o < NO; ++o) { lg[o] = __expf(lg[o]); sum += lg[o]; }
                const float rs = __builtin_amdgcn_rcpf(sum);
                #pragma unroll
                for (int o = 0; o < NO; ++o) {
                    const float cc = lg[o] * rs;
                    sacc[o][0] = fmaf(cc, xh[o][0], sacc[o][0]);
                    sacc[o][1] = fmaf(cc, xh[o][1], sacc[o][1]);
                    sacc[o][2] = fmaf(cc, xh[o][2], sacc[o][2]);
                    sacc[o][3] = fmaf(cc, xh[o][3], sacc[o][3]);
                }
            }
        }

        // prefetched loads have had a full round of compute to land
        asm volatile("s_waitcnt vmcnt(0)" ::: "memory");
        __syncthreads();
    }

    // cross-wave reduce, fp16-packed (uint2/o), lane-consecutive = conflict-free
    const float sc = UNIFORM ? 0.1f : 1.0f;
    #pragma unroll
    for (int o = 0; o < NO; ++o) {
        __half2 h01 = __floats2half2_rn(sacc[o][0] * sc, sacc[o][1] * sc);
        __half2 h23 = __floats2half2_rn(sacc[o][2] * sc, sacc[o][3] * sc);
        lds.red[w][o * 64 + l] =
            make_uint2(*reinterpret_cast<unsigned int*>(&h01),
                       *reinterpret_cast<unsigned int*>(&h23));
    }
    __syncthreads();
    unsigned short* base = s_part + ((size_t)nc * NBT + bt) * 2560;
    for (int g = tid; g < NO * 64; g += 256) {
        uint2 a0 = lds.red[0][g], a1 = lds.red[1][g],
              a2 = lds.red[2][g], a3 = lds.red[3][g];
        auto h2f2 = [](unsigned int u) {
            __half2 h = *reinterpret_cast<__half2*>(&u);
            return __half22float2(h);
        };
        float2 lo = h2f2(a0.x), l1 = h2f2(a1.x), l2 = h2f2(a2.x), l3 = h2f2(a3.x);
        float2 ho = h2f2(a0.y), h1 = h2f2(a1.y), h2 = h2f2(a2.y), h3 = h2f2(a3.y);
        float2 sl = { (lo.x + l1.x) + (l2.x + l3.x), (lo.y + l1.y) + (l2.y + l3.y) };
        float2 sh = { (ho.x + h1.x) + (h2.x + h3.x), (ho.y + h1.y) + (h2.y + h3.y) };
        __half2 p01 = __floats2half2_rn(sl.x, sl.y);
        __half2 p23 = __floats2half2_rn(sh.x, sh.y);
        *reinterpret_cast<uint2*>(base + (size_t)g * 4) =
            make_uint2(*reinterpret_cast<unsigned int*>(&p01),
                       *reinterpret_cast<unsigned int*>(&p23));
    }
}

// Reduce chunks + squash. Block bo = bt*10+o; thread t: l=t>>2, q=t&3.
template<int MODE>
__global__ __launch_bounds__(256) void caps_squash(
    const unsigned short* __restrict__ s_part,
    float* __restrict__ outsum,
    float* __restrict__ dout)
{
    __shared__ float sq[256];
    const int bo = blockIdx.x;
    const int t  = threadIdx.x;

    float s = 0.f;
    #pragma unroll 4
    for (int nc = 0; nc < NC; ++nc) {
        __half h = *reinterpret_cast<const __half*>(
            s_part + ((size_t)nc * NBT * NO + bo) * 256 + t);
        s += __half2float(h);
    }

    float n2 = s * s;
    n2 += __shfl_xor(n2, 1, 64);
    n2 += __shfl_xor(n2, 2, 64);       // q-pair reduced
    sq[t] = n2;
    __syncthreads();
    const int base = t & 63;
    n2 = (sq[base] + sq[64 + base]) + (sq[128 + base] + sq[192 + base]);

    const float norm  = sqrtf(n2);
    const float scale = n2 / ((1.f + n2) * (norm + 1e-8f));
    const float v = scale * s;

    if constexpr (MODE == 0) {
        outsum[(size_t)bo * 256 + t] = v;
    } else if constexpr (MODE == 1) {
        outsum[(size_t)bo * 256 + t] += v;
    } else {
        const int bt = bo / NO, o = bo - bt * NO;
        const int b16 = (t >> 2) & 15, hi = t >> 6, q = t & 3;
        dout[((size_t)(bt * BT + b16) * NO + o) * 16 + hi * 4 + q] = v;
    }
}

extern "C" void kernel_launch(void* const* d_in, const int* in_sizes, int n_in,
                              void* d_out, int out_size, void* d_ws, size_t ws_size,
                              hipStream_t stream) {
    const float* x = (const float*)d_in[0];   // [512][1152][8]
    const float* w = (const float*)d_in[1];   // [10][1152][16][8]
    float* out = (float*)d_out;               // [512][10][16]

    unsigned short* s_part = (unsigned short*)d_ws;
    float*          outsum = (float*)(s_part + SPART_H);
    unsigned short* xb     = (unsigned short*)(outsum + OUTSUM_F32);
    unsigned short* wb     = xb + XB_US;      // total ws ~= 17.2 MB

    cvt_xw<<<dim3(3168), dim3(256), 0, stream>>>(x, w, xb, wb);

    dim3 gI(NBT * NC), bI(256);               // 768 blocks = 3/CU
    dim3 gS(NBT * NO), bS(256);               // 320 blocks

    caps_iter<true ><<<gI, bI, 0, stream>>>(xb, wb, nullptr, s_part);
    caps_squash<0><<<gS, bS, 0, stream>>>(s_part, outsum, nullptr);
    caps_iter<false><<<gI, bI, 0, stream>>>(xb, wb, outsum, s_part);
    caps_squash<1><<<gS, bS, 0, stream>>>(s_part, outsum, nullptr);
    caps_iter<false><<<gI, bI, 0, stream>>>(xb, wb, outsum, s_part);
    caps_squash<2><<<gS, bS, 0, stream>>>(s_part, nullptr, out);
}